// Round 1
// baseline (2914.232 us; speedup 1.0000x reference)
//
#include <hip/hip_runtime.h>
#include <cstdint>
#include <cstdio>

// Problem constants (from reference): B=16, C=64, H=W=256, 3x3 convs pad=1.
#define BB 16
#define CC 64
#define HH 256
#define WW 256
#define TH 4     // output rows per block
#define COB 8    // output channels per block

__device__ __forceinline__ float lrelu(float x) { return x > 0.f ? x : 0.1f * x; }

// ---------------------------------------------------------------------------
// Tiny branch: mv[b][c] = sigmoid( tW2 @ leaky(t_b * tW1) )
//              kern[b][c*9+q] = leaky( kW2 @ leaky(t_b * kW1) )
// ---------------------------------------------------------------------------
__global__ void k_tiny(const float* __restrict__ t, const float* __restrict__ tW1,
                       const float* __restrict__ tW2, const float* __restrict__ kW1,
                       const float* __restrict__ kW2, float* __restrict__ mv,
                       float* __restrict__ kern) {
    int b = blockIdx.x;
    int c = threadIdx.x;  // 64 threads
    __shared__ float h1[CC], g1[CC];
    float ts = t[b];
    h1[c] = lrelu(ts * tW1[c]);
    g1[c] = lrelu(ts * kW1[c]);
    __syncthreads();
    float s = 0.f;
    for (int j = 0; j < CC; ++j) s = fmaf(tW2[c * CC + j], h1[j], s);
    mv[b * CC + c] = 1.f / (1.f + expf(-s));
    for (int q = 0; q < 9; ++q) {
        float s2 = 0.f;
        for (int j = 0; j < CC; ++j) s2 = fmaf(kW2[(c * 9 + q) * CC + j], g1[j], s2);
        kern[b * 9 * CC + c * 9 + q] = lrelu(s2);
    }
}

// ---------------------------------------------------------------------------
// 3x3 conv, stride 1, pad 1, 64->64 channels, optional bias+LeakyReLU.
// Block: 256 threads (one per w). Each block: (b, 8 c_out, 4 rows).
// Per c_in: stage 6 rows into LDS; weights via block-uniform (scalar) loads.
// grid = BB * (HH/TH) * (CC/COB) with cog fastest for x-band L2 reuse.
// ---------------------------------------------------------------------------
template <bool LEAKY>
__global__ __launch_bounds__(256) void k_conv3(const float* __restrict__ in,
                                               const float* __restrict__ wgt,
                                               const float* __restrict__ bias,
                                               float* __restrict__ out) {
    __shared__ float sx[6][WW];
    const int w = threadIdx.x;
    const unsigned bid = blockIdx.x;
    const int cog = bid & (CC / COB - 1);        // 0..7
    const int hb = (bid >> 3) & (HH / TH - 1);   // 0..63
    const int b = bid >> 9;                      // 0..15
    const int co0 = cog * COB;
    const int h0 = hb * TH;

    const float* inb = in + (size_t)b * CC * HH * WW;

    float acc[COB][TH];
#pragma unroll
    for (int co = 0; co < COB; ++co)
#pragma unroll
        for (int r = 0; r < TH; ++r) acc[co][r] = 0.f;

    for (int ci = 0; ci < CC; ++ci) {
        __syncthreads();  // previous-iter LDS readers done
        const float* src = inb + (size_t)ci * HH * WW;
#pragma unroll
        for (int r = 0; r < 6; ++r) {
            int hh = h0 - 1 + r;
            sx[r][w] = ((unsigned)hh < HH) ? src[hh * WW + w] : 0.f;
        }
        // block-uniform weight loads -> scalar regs
        float wt[COB][9];
#pragma unroll
        for (int co = 0; co < COB; ++co)
#pragma unroll
            for (int q = 0; q < 9; ++q)
                wt[co][q] = wgt[((co0 + co) * CC + ci) * 9 + q];
        __syncthreads();

        float xv[6][3];
#pragma unroll
        for (int r = 0; r < 6; ++r) {
            xv[r][0] = (w > 0) ? sx[r][w - 1] : 0.f;
            xv[r][1] = sx[r][w];
            xv[r][2] = (w < WW - 1) ? sx[r][w + 1] : 0.f;
        }
#pragma unroll
        for (int co = 0; co < COB; ++co)
#pragma unroll
            for (int r = 0; r < TH; ++r) {
                float s = acc[co][r];
#pragma unroll
                for (int dh = 0; dh < 3; ++dh)
#pragma unroll
                    for (int dw = 0; dw < 3; ++dw)
                        s = fmaf(xv[r + dh][dw], wt[co][dh * 3 + dw], s);
                acc[co][r] = s;
            }
    }

#pragma unroll
    for (int co = 0; co < COB; ++co) {
        float bv = bias[co0 + co];
#pragma unroll
        for (int r = 0; r < TH; ++r) {
            float v = acc[co][r] + bv;
            if (LEAKY) v = lrelu(v);
            out[((size_t)(b * CC + co0 + co) * HH + (h0 + r)) * WW + w] = v;
        }
    }
}

// ---------------------------------------------------------------------------
// Final fused pass: out = depthwise(f2, kern)*mv + conv3x3(x, cW) + cb
// Same conv structure as k_conv3 for the cW part; depthwise reads f2 directly
// (9 loads/output, L1-friendly); kern/mv/cb are block-uniform scalars.
// ---------------------------------------------------------------------------
__global__ __launch_bounds__(256) void k_final(const float* __restrict__ x,
                                               const float* __restrict__ cw,
                                               const float* __restrict__ cb,
                                               const float* __restrict__ f2,
                                               const float* __restrict__ mv,
                                               const float* __restrict__ kern,
                                               float* __restrict__ out) {
    __shared__ float sx[6][WW];
    const int w = threadIdx.x;
    const unsigned bid = blockIdx.x;
    const int cog = bid & (CC / COB - 1);
    const int hb = (bid >> 3) & (HH / TH - 1);
    const int b = bid >> 9;
    const int co0 = cog * COB;
    const int h0 = hb * TH;

    const float* inb = x + (size_t)b * CC * HH * WW;

    float acc[COB][TH];
#pragma unroll
    for (int co = 0; co < COB; ++co)
#pragma unroll
        for (int r = 0; r < TH; ++r) acc[co][r] = 0.f;

    for (int ci = 0; ci < CC; ++ci) {
        __syncthreads();
        const float* src = inb + (size_t)ci * HH * WW;
#pragma unroll
        for (int r = 0; r < 6; ++r) {
            int hh = h0 - 1 + r;
            sx[r][w] = ((unsigned)hh < HH) ? src[hh * WW + w] : 0.f;
        }
        float wt[COB][9];
#pragma unroll
        for (int co = 0; co < COB; ++co)
#pragma unroll
            for (int q = 0; q < 9; ++q)
                wt[co][q] = cw[((co0 + co) * CC + ci) * 9 + q];
        __syncthreads();

        float xv[6][3];
#pragma unroll
        for (int r = 0; r < 6; ++r) {
            xv[r][0] = (w > 0) ? sx[r][w - 1] : 0.f;
            xv[r][1] = sx[r][w];
            xv[r][2] = (w < WW - 1) ? sx[r][w + 1] : 0.f;
        }
#pragma unroll
        for (int co = 0; co < COB; ++co)
#pragma unroll
            for (int r = 0; r < TH; ++r) {
                float s = acc[co][r];
#pragma unroll
                for (int dh = 0; dh < 3; ++dh)
#pragma unroll
                    for (int dw = 0; dw < 3; ++dw)
                        s = fmaf(xv[r + dh][dw], wt[co][dh * 3 + dw], s);
                acc[co][r] = s;
            }
    }

#pragma unroll
    for (int co = 0; co < COB; ++co) {
        const int c = co0 + co;
        const float mvv = mv[b * CC + c];
        const float bv = cb[c];
        const float* f2c = f2 + (size_t)(b * CC + c) * HH * WW;
        const float* kc = kern + b * 9 * CC + c * 9;
#pragma unroll
        for (int r = 0; r < TH; ++r) {
            const int h = h0 + r;
            float dwv = 0.f;
#pragma unroll
            for (int dh = -1; dh <= 1; ++dh) {
                int hh = h + dh;
                if ((unsigned)hh >= HH) continue;
#pragma unroll
                for (int dw = -1; dw <= 1; ++dw) {
                    int ww = w + dw;
                    if ((unsigned)ww >= WW) continue;
                    dwv = fmaf(kc[(dh + 1) * 3 + (dw + 1)], f2c[hh * WW + ww], dwv);
                }
            }
            out[((size_t)(b * CC + c) * HH + h) * WW + w] = dwv * mvv + acc[co][r] + bv;
        }
    }
}

// ---------------------------------------------------------------------------
extern "C" void kernel_launch(void* const* d_in, const int* in_sizes, int n_in,
                              void* d_out, int out_size, void* d_ws, size_t ws_size,
                              hipStream_t stream) {
    const float* x   = (const float*)d_in[0];
    const float* t   = (const float*)d_in[1];
    const float* tW1 = (const float*)d_in[2];
    const float* tW2 = (const float*)d_in[3];
    const float* fW1 = (const float*)d_in[4];
    const float* fb1 = (const float*)d_in[5];
    const float* fW2 = (const float*)d_in[6];
    const float* fb2 = (const float*)d_in[7];
    const float* kW1 = (const float*)d_in[8];
    const float* kW2 = (const float*)d_in[9];
    const float* cW  = (const float*)d_in[10];
    const float* cb  = (const float*)d_in[11];
    float* out = (float*)d_out;

    // Workspace layout: [mv 4KB][kern ~37KB][pad to 1MB][f2 256MB]
    // Requires ws_size >= 1MB + 256MB.
    char* ws = (char*)d_ws;
    float* mv   = (float*)ws;
    float* kern = (float*)(ws + 4096);
    float* f2   = (float*)(ws + (1u << 20));
    float* f1   = out;  // d_out doubles as f1 scratch (overwritten by final pass)

    k_tiny<<<dim3(BB), dim3(CC), 0, stream>>>(t, tW1, tW2, kW1, kW2, mv, kern);

    dim3 grid(BB * (HH / TH) * (CC / COB));  // 8192 blocks, cog fastest
    k_conv3<true><<<grid, dim3(256), 0, stream>>>(x, fW1, fb1, f1);
    k_conv3<true><<<grid, dim3(256), 0, stream>>>(f1, fW2, fb2, f2);
    k_final<<<grid, dim3(256), 0, stream>>>(x, cW, cb, f2, mv, kern, out);
}

// Round 2
// 967.579 us; speedup vs baseline: 3.0119x; 3.0119x over previous
//
#include <hip/hip_runtime.h>
#include <cstdint>

// B=16, C=64, H=W=256. Three 3x3 convs via bf16 MFMA implicit GEMM.
using short8  = __attribute__((ext_vector_type(8))) short;
using short4v = __attribute__((ext_vector_type(4))) short;
using f32x16  = __attribute__((ext_vector_type(16))) float;
using float4v = __attribute__((ext_vector_type(4))) float;
typedef unsigned short ushort_t;

__device__ __forceinline__ float lrelu(float x) { return x > 0.f ? x : 0.1f * x; }

__device__ __forceinline__ ushort_t f2bf(float f) {
    union { float f; unsigned u; } v; v.f = f;
    unsigned r = (v.u + 0x7FFFu + ((v.u >> 16) & 1u)) >> 16;
    return (ushort_t)r;
}
__device__ __forceinline__ float bf2f(ushort_t b) {
    union { unsigned u; float f; } v; v.u = ((unsigned)b) << 16; return v.f;
}

// ---------------------------------------------------------------------------
// Tiny branch: mv[b][c], kern[b][c*9+q]
// ---------------------------------------------------------------------------
__global__ void k_tiny(const float* __restrict__ t, const float* __restrict__ tW1,
                       const float* __restrict__ tW2, const float* __restrict__ kW1,
                       const float* __restrict__ kW2, float* __restrict__ mv,
                       float* __restrict__ kern) {
    int b = blockIdx.x;
    int c = threadIdx.x;  // 64
    __shared__ float h1[64], g1[64];
    float ts = t[b];
    h1[c] = lrelu(ts * tW1[c]);
    g1[c] = lrelu(ts * kW1[c]);
    __syncthreads();
    float s = 0.f;
    for (int j = 0; j < 64; ++j) s = fmaf(tW2[c * 64 + j], h1[j], s);
    mv[b * 64 + c] = 1.f / (1.f + expf(-s));
    for (int q = 0; q < 9; ++q) {
        float s2 = 0.f;
        for (int j = 0; j < 64; ++j) s2 = fmaf(kW2[(c * 9 + q) * 64 + j], g1[j], s2);
        kern[b * 576 + c * 9 + q] = lrelu(s2);
    }
}

// ---------------------------------------------------------------------------
// Pack three 64x64x3x3 weight tensors into MFMA A-fragment order (bf16).
// Frag layout: flat = (((t*2+ch)*2+kc)*2+ct)*512 + lane*8 + j
//   element  = W[co = ct*32 + (lane&31)][ci = ch*32 + kc*16 + (lane>>5)*8 + j], tap t
// ---------------------------------------------------------------------------
__global__ void k_pack(const float* __restrict__ w1, const float* __restrict__ w2,
                       const float* __restrict__ w3, ushort_t* __restrict__ wp) {
    int idx = blockIdx.x * 256 + threadIdx.x;
    if (idx >= 3 * 36864) return;
    int conv = idx / 36864, r = idx % 36864;
    const float* W = conv == 0 ? w1 : (conv == 1 ? w2 : w3);
    int j = r & 7, lane = (r >> 3) & 63, ct = (r >> 9) & 1, kc = (r >> 10) & 1,
        ch = (r >> 11) & 1, t = r >> 12;
    int co = ct * 32 + (lane & 31);
    int ci = ch * 32 + kc * 16 + (lane >> 5) * 8 + j;
    wp[idx] = f2bf(W[(co * 64 + ci) * 9 + t]);
}

// ---------------------------------------------------------------------------
// Transpose x: fp32 NCHW -> bf16 NHWC. Block = (b,h). Gather loads (L1/L2
// absorb the strided reads), perfectly coalesced 16B stores.
// ---------------------------------------------------------------------------
__global__ __launch_bounds__(256) void k_tr(const float* __restrict__ x,
                                            ushort_t* __restrict__ xbf) {
    int bid = blockIdx.x;
    int h = bid & 255, b = bid >> 8;
    int t = threadIdx.x;
    for (int it = 0; it < 8; ++it) {
        int idx = t + it * 256;          // 0..2047 : (w, g)
        int g = idx & 7, w = idx >> 3;
        const float* src = x + (((size_t)(b * 64 + g * 8) * 256 + h) * 256 + w);
        short8 v;
#pragma unroll
        for (int j = 0; j < 8; ++j) v[j] = (short)f2bf(src[(size_t)j * 65536]);
        *(short8*)(xbf + (((size_t)(b * 256 + h) * 256 + w) * 64 + g * 8)) = v;
    }
}

// ---------------------------------------------------------------------------
// 3x3 conv 64->64 via v_mfma_f32_32x32x16_bf16.
// Block = (b, h): 4 waves, each computes 64 c_out x 64 pixels.
// LDS: [3 rows][130 pixel-pairs][8 swizzled 16B slots] = 48.75 KB, 2 ci-chunks.
// A-frags from packed weights (global, L2-resident); B-frags ds_read_b128.
// ---------------------------------------------------------------------------
template <bool LEAKY, bool NHWC>
__global__ __launch_bounds__(256, 3) void k_conv(const ushort_t* __restrict__ in,
                                                 const ushort_t* __restrict__ wp,
                                                 const float* __restrict__ bias,
                                                 void* __restrict__ outp) {
    __shared__ __align__(16) short xs[3 * 130 * 64];  // 49920 B
    const int tid = threadIdx.x;
    const int lane = tid & 63;
    const int wv = tid >> 6;
    const int bid = blockIdx.x;
    const int h = bid & 255, b = bid >> 8;
    const int l31 = lane & 31, lhi = lane >> 5;
    const int pw0 = wv * 64;

    f32x16 acc[2][2];
#pragma unroll
    for (int a = 0; a < 2; ++a)
#pragma unroll
        for (int c = 0; c < 2; ++c) acc[a][c] = (f32x16)0.0f;

    for (int ch = 0; ch < 2; ++ch) {
        __syncthreads();
        // stage 3 rows x 258 pixels x 32 ci (bf16) with XOR-swizzled slots
        for (int i = tid; i < 3 * 260 * 4; i += 256) {
            int g = i & 3;
            int p = (i >> 2) % 260;
            int r = (i >> 2) / 260;
            if (p >= 258) continue;
            int hs = h + r - 1, ws = p - 1;
            short8 v = (short8)0;
            if ((unsigned)hs < 256u && (unsigned)ws < 256u)
                v = *(const short8*)(in + (((size_t)(b * 256 + hs) * 256 + ws) * 64 +
                                           ch * 32 + g * 8));
            int slot = ((p & 1) * 4 + g) ^ ((p >> 1) & 7);
            *(short8*)(xs + ((r * 130 + (p >> 1)) * 8 + slot) * 8) = v;
        }
        __syncthreads();

#pragma unroll
        for (int t = 0; t < 9; ++t) {
            const int r = t / 3, dw = t % 3;
#pragma unroll
            for (int kc = 0; kc < 2; ++kc) {
                const ushort_t* wpf = wp + (((((t * 2 + ch) * 2 + kc) * 2) * 64 + lane) * 8);
                short8 a0 = *(const short8*)(wpf);
                short8 a1 = *(const short8*)(wpf + 512);
                const int g = kc * 2 + lhi;
#pragma unroll
                for (int pt = 0; pt < 2; ++pt) {
                    int p = pw0 + pt * 32 + l31 + dw;
                    int slot = ((p & 1) * 4 + g) ^ ((p >> 1) & 7);
                    short8 bf = *(const short8*)(xs + ((r * 130 + (p >> 1)) * 8 + slot) * 8);
                    acc[0][pt] = __builtin_amdgcn_mfma_f32_32x32x16_bf16(a0, bf, acc[0][pt], 0, 0, 0);
                    acc[1][pt] = __builtin_amdgcn_mfma_f32_32x32x16_bf16(a1, bf, acc[1][pt], 0, 0, 0);
                }
            }
        }
    }

    // Epilogue. D layout: col(pix)=lane&31, row(co)=(reg&3)+8*(reg>>2)+4*(lane>>5)
    const int co_b = 4 * lhi;
    if (NHWC) {
        ushort_t* outb = (ushort_t*)outp + ((size_t)(b * 256 + h) * 256) * 64;
#pragma unroll
        for (int ct = 0; ct < 2; ++ct)
#pragma unroll
            for (int pt = 0; pt < 2; ++pt) {
                int pix = pw0 + pt * 32 + l31;
                ushort_t* po = outb + (size_t)pix * 64 + ct * 32 + co_b;
#pragma unroll
                for (int q = 0; q < 4; ++q) {
                    float4v bv = *(const float4v*)(bias + ct * 32 + co_b + 8 * q);
                    short4v sv;
#pragma unroll
                    for (int m = 0; m < 4; ++m) {
                        float v = acc[ct][pt][q * 4 + m] + bv[m];
                        if (LEAKY) v = lrelu(v);
                        sv[m] = (short)f2bf(v);
                    }
                    *(short4v*)(po + 8 * q) = sv;
                }
            }
    } else {
        float* po = (float*)outp;
#pragma unroll
        for (int ct = 0; ct < 2; ++ct)
#pragma unroll
            for (int pt = 0; pt < 2; ++pt) {
                int pix = pw0 + pt * 32 + l31;
#pragma unroll
                for (int q = 0; q < 4; ++q) {
                    float4v bv = *(const float4v*)(bias + ct * 32 + co_b + 8 * q);
#pragma unroll
                    for (int m = 0; m < 4; ++m) {
                        int co = ct * 32 + co_b + 8 * q + m;
                        float v = acc[ct][pt][q * 4 + m] + bv[m];
                        if (LEAKY) v = lrelu(v);
                        po[((size_t)(b * 64 + co) << 16) + h * 256 + pix] = v;
                    }
                }
            }
    }
}

// ---------------------------------------------------------------------------
// Final: out += depthwise(f2bf, kern) * mv   (out already holds cW-conv + cb)
// Block = (b,h); thread = w. kern/mv are wave-uniform -> scalar loads.
// ---------------------------------------------------------------------------
__global__ __launch_bounds__(256) void k_dw(const ushort_t* __restrict__ f2,
                                            const float* __restrict__ kern,
                                            const float* __restrict__ mv,
                                            float* __restrict__ out) {
    int bid = blockIdx.x;
    int h = bid & 255, b = bid >> 8;
    int w = threadIdx.x;
    float acc[64];
#pragma unroll
    for (int c = 0; c < 64; ++c) acc[c] = 0.f;
    const float* kb = kern + b * 576;
#pragma unroll
    for (int t = 0; t < 9; ++t) {
        int dh = t / 3 - 1, dw = t % 3 - 1;
        int hs = h + dh;
        if ((unsigned)hs >= 256u) continue;
        int ws = w + dw;
        bool ok = (unsigned)ws < 256u;
        const ushort_t* src = f2 + ((size_t)(b * 256 + hs) * 256 + (ok ? ws : 0)) * 64;
#pragma unroll
        for (int g = 0; g < 8; ++g) {
            short8 v = *(const short8*)(src + g * 8);
#pragma unroll
            for (int j = 0; j < 8; ++j) {
                float xv = ok ? bf2f((ushort_t)v[j]) : 0.f;
                acc[g * 8 + j] = fmaf(kb[(g * 8 + j) * 9 + t], xv, acc[g * 8 + j]);
            }
        }
    }
    size_t ob = ((size_t)(b * 64)) << 16;
#pragma unroll
    for (int c = 0; c < 64; ++c) {
        size_t oi = ob + ((size_t)c << 16) + h * 256 + w;
        out[oi] = fmaf(acc[c], mv[b * 64 + c], out[oi]);
    }
}

// ---------------------------------------------------------------------------
extern "C" void kernel_launch(void* const* d_in, const int* in_sizes, int n_in,
                              void* d_out, int out_size, void* d_ws, size_t ws_size,
                              hipStream_t stream) {
    const float* x   = (const float*)d_in[0];
    const float* t   = (const float*)d_in[1];
    const float* tW1 = (const float*)d_in[2];
    const float* tW2 = (const float*)d_in[3];
    const float* fW1 = (const float*)d_in[4];
    const float* fb1 = (const float*)d_in[5];
    const float* fW2 = (const float*)d_in[6];
    const float* fb2 = (const float*)d_in[7];
    const float* kW1 = (const float*)d_in[8];
    const float* kW2 = (const float*)d_in[9];
    const float* cW  = (const float*)d_in[10];
    const float* cb  = (const float*)d_in[11];

    // ws: [mv 4KB][kern 36KB][wpack @64KB, 216KB][xbf @1MB, 128MB][f2bf @1MB+128MB, 128MB]
    char* ws = (char*)d_ws;
    float*    mv   = (float*)ws;
    float*    kern = (float*)(ws + 4096);
    ushort_t* wp   = (ushort_t*)(ws + 65536);
    ushort_t* xbf  = (ushort_t*)(ws + (1u << 20));
    ushort_t* f2bf_ = (ushort_t*)(ws + (1u << 20) + ((size_t)128 << 20));
    ushort_t* f1bf = (ushort_t*)d_out;  // first 128MB of d_out as scratch
    float*    out  = (float*)d_out;

    k_tiny<<<dim3(16), dim3(64), 0, stream>>>(t, tW1, tW2, kW1, kW2, mv, kern);
    k_pack<<<dim3((3 * 36864 + 255) / 256), dim3(256), 0, stream>>>(fW1, fW2, cW, wp);
    k_tr<<<dim3(4096), dim3(256), 0, stream>>>(x, xbf);

    k_conv<true, true><<<dim3(4096), dim3(256), 0, stream>>>(xbf, wp, fb1, (void*)f1bf);
    k_conv<true, true><<<dim3(4096), dim3(256), 0, stream>>>(f1bf, wp + 36864, fb2, (void*)f2bf_);
    k_conv<false, false><<<dim3(4096), dim3(256), 0, stream>>>(xbf, wp + 2 * 36864, cb, (void*)out);
    k_dw<<<dim3(4096), dim3(256), 0, stream>>>(f2bf_, kern, mv, out);
}